// Round 13
// baseline (8160.214 us; speedup 1.0000x reference)
//
#include <hip/hip_runtime.h>
#include <math.h>

#define Bb 128
#define Tt 1024
#define Ff 128
#define Hh 256
#define Oo 128

#define NW 192u  // resident weight u32s per thread

// d_ws layout (u32 words)
#define P_PACK 0u
#define PACK_SZ  (2u * NW * 512u)          // 196608
#define P_HX   (P_PACK + PACK_SZ)          // [parity2][row2][128 blk][64] u64 tagged
#define HX_U32 (2u * 2u * 128u * 64u * 2u) // 65536 u32
#define P_PART (P_HX + HX_U32)

typedef _Float16 half2_t __attribute__((ext_vector_type(2)));
union U32H2 { unsigned u; half2_t h; };

__device__ __forceinline__ float dot2f(unsigned wu, unsigned hu, float acc) {
    U32H2 a, b; a.u = wu; b.u = hu;
#if __has_builtin(__builtin_amdgcn_fdot2)
    return __builtin_amdgcn_fdot2(a.h, b.h, acc, false);
#else
    return acc + (float)a.h.x * (float)b.h.x + (float)a.h.y * (float)b.h.y;
#endif
}

// LDS-only barrier: global store acks / prefetch loads stay in flight.
#define BAR_LGKM() do {                                              \
    asm volatile("s_waitcnt lgkmcnt(0)" ::: "memory");               \
    __builtin_amdgcn_s_barrier();                                    \
    asm volatile("" ::: "memory");                                   \
} while (0)

// R12-identical pack: dst[(role*NW + j)*512 + tid]
__global__ void pack_kernel(const float* __restrict__ wih, const float* __restrict__ whh,
                            const float* __restrict__ wsel, const float* __restrict__ wout,
                            unsigned* __restrict__ dst) {
    unsigned pid = blockIdx.x * 256 + threadIdx.x;
    if (pid >= 2u * NW * 512u) return;
    int tid = pid & 511;
    int j = (pid >> 9) % NW;
    int role = pid / (NW * 512u);
    int d = tid & 127, q = tid >> 7;
    int orow = tid & 63, oct = tid >> 6;
    const float* src; int idx0;
    if (j < 48) {
        int g = j >> 4, m = j & 15;
        int R = g * 256 + role * 128 + d;
        src = whh; idx0 = R * 256 + 2 * (role * 64 + q * 16 + m);
    } else if (j < 96) {
        int jj = j - 48, g = jj >> 4, m = jj & 15;
        int R = g * 256 + role * 128 + d;
        src = whh; idx0 = R * 256 + 2 * ((1 - role) * 64 + q * 16 + m);
    } else if (j < 144) {
        int jj = j - 96, g = jj >> 4, m = jj & 15;
        int R = g * 256 + role * 128 + d;
        src = wih; idx0 = R * 128 + 2 * (16 * q + m);
    } else if (j < 160) {
        int jj = j - 144;
        src = wsel; idx0 = d * 256 + 2 * (role * 64 + q * 16 + jj);
    } else if (j < 176) {
        int jj = j - 160;
        src = wsel; idx0 = d * 256 + 2 * ((1 - role) * 64 + q * 16 + jj);
    } else {
        int jj = j - 176;
        int R = role * 64 + orow;
        src = wout; idx0 = R * 256 + 2 * (oct * 16 + jj);
    }
    U32H2 v; v.h = (half2_t){ (_Float16)src[idx0], (_Float16)src[idx0 + 1] };
    dst[pid] = v.u;
}

__global__ void zero_hx(unsigned* __restrict__ hx) {
    hx[blockIdx.x * 256 + threadIdx.x] = 0u;
}

__global__ __launch_bounds__(512)
void gru_kernel(const float* __restrict__ x, const float* __restrict__ noise,
                const float* __restrict__ bih, const float* __restrict__ bhh,
                const float* __restrict__ bout, const float* __restrict__ bsel,
                unsigned* __restrict__ wsu,
                float* __restrict__ outputs, float* __restrict__ selw,
                float* __restrict__ partials) {
    const int bid = blockIdx.x;           // 0..127
    const int p   = bid & 63;
    const int role = bid >> 6;            // partner = bid ^ 64 (same XCD mod 8; perf only)
    const int rA = p, rB = 64 + p;        // two independent rows per pair
    const int tid = threadIdx.x;
    const int d = tid & 127, q = tid >> 7;
    const int orow = tid & 63, oct = tid >> 6;

    __shared__ unsigned h2uA[128], h2uB[128];
    __shared__ unsigned wxuA[64],  wxuB[64];
    __shared__ float redA[512 * 5], redB[512 * 5];

    // ---- resident weights (R12 layout) ----
    unsigned whho[48], whhp[48], wih2[48], wselo[16], wselp[16], wout2[16];
    const unsigned base = (unsigned)(role * NW) * 512u + (unsigned)tid;
    const unsigned* __restrict__ pk = wsu + P_PACK;
    #pragma unroll
    for (int j = 0; j < 48; j++) whho[j] = pk[base + j * 512];
    #pragma unroll
    for (int j = 0; j < 48; j++) whhp[j] = pk[base + (48 + j) * 512];
    #pragma unroll
    for (int j = 0; j < 48; j++) wih2[j] = pk[base + (96 + j) * 512];
    #pragma unroll
    for (int j = 0; j < 16; j++) wselo[j] = pk[base + (144 + j) * 512];
    #pragma unroll
    for (int j = 0; j < 16; j++) wselp[j] = pk[base + (160 + j) * 512];
    #pragma unroll
    for (int j = 0; j < 16; j++) wout2[j] = pk[base + (176 + j) * 512];
    #pragma unroll
    for (int j = 0; j < 48; j++) asm volatile("" : "+v"(whho[j]));
    #pragma unroll
    for (int j = 0; j < 48; j++) asm volatile("" : "+v"(whhp[j]));
    #pragma unroll
    for (int j = 0; j < 48; j++) asm volatile("" : "+v"(wih2[j]));
    #pragma unroll
    for (int j = 0; j < 16; j++) asm volatile("" : "+v"(wselo[j]));
    #pragma unroll
    for (int j = 0; j < 16; j++) asm volatile("" : "+v"(wselp[j]));
    #pragma unroll
    for (int j = 0; j < 16; j++) asm volatile("" : "+v"(wout2[j]));

    // ---- biases ----
    float bias_r = 0.f, bias_z = 0.f, bias_in = 0.f, bias_hn = 0.f, bsel_d = 0.f, bout_o = 0.f;
    if (tid < 128) {
        int gr = role * 128 + d;
        bias_r  = bih[gr]       + bhh[gr];
        bias_z  = bih[256 + gr] + bhh[256 + gr];
        bias_in = bih[512 + gr];
        bias_hn = bhh[512 + gr];
        bsel_d  = bsel[d];
    }
    if (tid < 64) bout_o = bout[role * 64 + tid];

    // ---- init both rows ----
    if (tid < 128) {
        h2uA[tid] = 0u; h2uB[tid] = 0u;
        float xa = x[(size_t)rA * Tt * Ff + tid];
        float xap = __shfl_xor(xa, 1, 64);
        float xb = x[(size_t)rB * Tt * Ff + tid];
        float xbp = __shfl_xor(xb, 1, 64);
        if (!(tid & 1)) {
            U32H2 v; v.h = (half2_t){ (_Float16)xa, (_Float16)xap }; wxuA[tid >> 1] = v.u;
            U32H2 w; w.h = (half2_t){ (_Float16)xb, (_Float16)xbp }; wxuB[tid >> 1] = w.u;
        }
        if (role == 0) {
            selw[(size_t)rA * Ff + tid] = 1.0f;
            selw[(size_t)rB * Ff + tid] = 1.0f;
        }
    }
    __syncthreads();

    unsigned long long* hxq = (unsigned long long*)(wsu + P_HX);

    float h_oldA = 0.f, h_oldB = 0.f, ssumA = 0.f, ssumB = 0.f;
    float aorA = 0.f, aozA = 0.f, aohnA = 0.f;
    float aorB = 0.f, aozB = 0.f, aohnB = 0.f;
    size_t xbaseA  = ((size_t)rA * Tt + 1) * Ff + d;
    size_t xbaseB  = ((size_t)rB * Tt + 1) * Ff + d;
    size_t nzbaseA = (size_t)rA * Ff + d;
    size_t nzbaseB = (size_t)rB * Ff + d;
    size_t swbaseA = ((size_t)Bb + rA) * Ff + d;
    size_t swbaseB = ((size_t)Bb + rB) * Ff + d;
    size_t obaseA  = (size_t)rA * Oo + role * 64 + orow;
    size_t obaseB  = (size_t)rB * Oo + role * 64 + orow;

    const uint4* h4A = (const uint4*)h2uA;
    const uint4* h4B = (const uint4*)h2uB;
    const uint4* w4A = (const uint4*)wxuA;
    const uint4* w4B = (const uint4*)wxuB;

// gates(t) = pipelined gh_own + gh_partner + gi; finalize h_own(t); tagged publish
#define GATES_PUB(S)                                                            \
{                                                                               \
    float a_r = aor##S, a_z = aoz##S, a_in = 0.f, a_hn = aohn##S;               \
    _Pragma("unroll")                                                           \
    for (int mm = 0; mm < 4; ++mm) {                                            \
        uint4 hv = h4##S[(role ^ 1) * 16 + q * 4 + mm];                         \
        unsigned hh[4] = { hv.x, hv.y, hv.z, hv.w };                            \
        _Pragma("unroll")                                                       \
        for (int i = 0; i < 4; i++) {                                           \
            a_r  = dot2f(whhp[mm * 4 + i],      hh[i], a_r);                    \
            a_z  = dot2f(whhp[16 + mm * 4 + i], hh[i], a_z);                    \
            a_hn = dot2f(whhp[32 + mm * 4 + i], hh[i], a_hn);                   \
        }                                                                       \
    }                                                                           \
    _Pragma("unroll")                                                           \
    for (int pp = 0; pp < 4; ++pp) {                                            \
        uint4 wv = w4##S[4 * q + pp];                                           \
        unsigned ww[4] = { wv.x, wv.y, wv.z, wv.w };                            \
        _Pragma("unroll")                                                       \
        for (int i = 0; i < 4; i++) {                                           \
            a_r  = dot2f(wih2[pp * 4 + i],      ww[i], a_r);                    \
            a_z  = dot2f(wih2[16 + pp * 4 + i], ww[i], a_z);                    \
            a_in = dot2f(wih2[32 + pp * 4 + i], ww[i], a_in);                   \
        }                                                                       \
    }                                                                           \
    red##S[tid * 5 + 0] = a_r; red##S[tid * 5 + 1] = a_z;                       \
    red##S[tid * 5 + 2] = a_in; red##S[tid * 5 + 3] = a_hn;                     \
    BAR_LGKM();                                                                 \
    if (tid < 128) {                                                            \
        float rr = bias_r, zz = bias_z, ii = bias_in, hh2 = bias_hn;            \
        _Pragma("unroll")                                                       \
        for (int qq = 0; qq < 4; qq++) {                                        \
            int b0 = (qq * 128 + d) * 5;                                        \
            rr += red##S[b0]; zz += red##S[b0 + 1];                             \
            ii += red##S[b0 + 2]; hh2 += red##S[b0 + 3];                        \
        }                                                                       \
        float r_ = 1.f / (1.f + expf(-rr));                                     \
        float z_ = 1.f / (1.f + expf(-zz));                                     \
        float n_ = tanhf(ii + r_ * hh2);                                        \
        float hn2 = (1.f - z_) * n_ + z_ * h_old##S;                            \
        h_old##S = hn2;                                                         \
        float hp = __shfl_xor(hn2, 1, 64);                                      \
        if (!(d & 1)) {                                                         \
            U32H2 v; v.h = (half2_t){ (_Float16)hn2, (_Float16)hp };            \
            h2u##S[role * 64 + (d >> 1)] = v.u;                                 \
            unsigned long long msg =                                            \
                ((unsigned long long)(unsigned)(t + 1) << 32) | v.u;            \
            __hip_atomic_store(&hxq[mbMy##S + (unsigned)(d >> 1)], msg,         \
                               __ATOMIC_RELAXED, __HIP_MEMORY_SCOPE_AGENT);     \
        }                                                                       \
    }                                                                           \
    BAR_LGKM();                                                                 \
}

// flight window: gh_own(t+1) + own-half sel/out partials
#define OWN(S)                                                                  \
{                                                                               \
    aor##S = 0.f; aoz##S = 0.f; aohn##S = 0.f;                                  \
    psel##S = 0.f; pout##S = 0.f;                                               \
    _Pragma("unroll")                                                           \
    for (int mm = 0; mm < 4; ++mm) {                                            \
        uint4 hv = h4##S[role * 16 + q * 4 + mm];                               \
        unsigned hh[4] = { hv.x, hv.y, hv.z, hv.w };                            \
        _Pragma("unroll")                                                       \
        for (int i = 0; i < 4; i++) {                                           \
            aor##S  = dot2f(whho[mm * 4 + i],      hh[i], aor##S);              \
            aoz##S  = dot2f(whho[16 + mm * 4 + i], hh[i], aoz##S);              \
            aohn##S = dot2f(whho[32 + mm * 4 + i], hh[i], aohn##S);             \
            psel##S = dot2f(wselo[mm * 4 + i],     hh[i], psel##S);             \
        }                                                                       \
    }                                                                           \
    if ((oct >> 2) == role) {                                                   \
        _Pragma("unroll")                                                       \
        for (int mm = 0; mm < 4; ++mm) {                                        \
            uint4 hv = h4##S[oct * 4 + mm];                                     \
            unsigned hh[4] = { hv.x, hv.y, hv.z, hv.w };                        \
            _Pragma("unroll")                                                   \
            for (int i = 0; i < 4; i++)                                         \
                pout##S = dot2f(wout2[mm * 4 + i], hh[i], pout##S);             \
        }                                                                       \
    }                                                                           \
}

#define POLL(S)                                                                 \
{                                                                               \
    if (tid < 64) {                                                             \
        unsigned long long msg;                                                 \
        do {                                                                    \
            msg = __hip_atomic_load(&hxq[mbP##S + (unsigned)tid],               \
                                    __ATOMIC_RELAXED, __HIP_MEMORY_SCOPE_AGENT);\
            if ((unsigned)(msg >> 32) >= (unsigned)(t + 1)) break;              \
            __builtin_amdgcn_s_sleep(1);                                        \
        } while (1);                                                            \
        h2u##S[(role ^ 1) * 64 + tid] = (unsigned)msg;                          \
    }                                                                           \
    BAR_LGKM();                                                                 \
}

// partner-half sel/out; outputs(t); w(t+1); wx(t+1)
#define TAIL(S)                                                                 \
{                                                                               \
    _Pragma("unroll")                                                           \
    for (int mm = 0; mm < 4; ++mm) {                                            \
        uint4 hv = h4##S[(role ^ 1) * 16 + q * 4 + mm];                         \
        unsigned hh[4] = { hv.x, hv.y, hv.z, hv.w };                            \
        _Pragma("unroll")                                                       \
        for (int i = 0; i < 4; i++)                                             \
            psel##S = dot2f(wselp[mm * 4 + i], hh[i], psel##S);                 \
    }                                                                           \
    if ((oct >> 2) != role) {                                                   \
        _Pragma("unroll")                                                       \
        for (int mm = 0; mm < 4; ++mm) {                                        \
            uint4 hv = h4##S[oct * 4 + mm];                                     \
            unsigned hh[4] = { hv.x, hv.y, hv.z, hv.w };                        \
            _Pragma("unroll")                                                   \
            for (int i = 0; i < 4; i++)                                         \
                pout##S = dot2f(wout2[mm * 4 + i], hh[i], pout##S);             \
        }                                                                       \
    }                                                                           \
    red##S[tid * 5 + 0] = psel##S; red##S[tid * 5 + 1] = pout##S;               \
    BAR_LGKM();                                                                 \
    if (tid < 64) {                                                             \
        float acc = bout_o;                                                     \
        _Pragma("unroll")                                                       \
        for (int j2 = 0; j2 < 8; j2++) acc += red##S[(j2 * 64 + tid) * 5 + 1];  \
        outputs[obase##S] = acc;                                                \
    }                                                                           \
    if (tid < 128 && t < Tt - 1) {                                              \
        float lg = bsel_d;                                                      \
        _Pragma("unroll")                                                       \
        for (int qq = 0; qq < 4; qq++) lg += red##S[(qq * 128 + d) * 5 + 0];    \
        float arg = (lg + logf(nzv##S + 1e-20f)                                 \
                        - logf(1.f - nzv##S + 1e-20f)) * 20.0f;                 \
        float w = 1.f / (1.f + expf(-arg));                                     \
        if (role == 0) { selw[swbase##S] = w; ssum##S += w; }                   \
        float wxv = w * xv##S;                                                  \
        float wp = __shfl_xor(wxv, 1, 64);                                      \
        if (!(d & 1)) {                                                         \
            U32H2 v; v.h = (half2_t){ (_Float16)wxv, (_Float16)wp };            \
            wxu##S[d >> 1] = v.u;                                               \
        }                                                                       \
    }                                                                           \
}

    for (int t = 0; t < Tt; ++t) {
        const unsigned mbMyA = (((unsigned)(t & 1) * 2u + 0u) * 128u + (unsigned)(p * 2 + role)) * 64u;
        const unsigned mbPA  = (((unsigned)(t & 1) * 2u + 0u) * 128u + (unsigned)(p * 2 + (role ^ 1))) * 64u;
        const unsigned mbMyB = (((unsigned)(t & 1) * 2u + 1u) * 128u + (unsigned)(p * 2 + role)) * 64u;
        const unsigned mbPB  = (((unsigned)(t & 1) * 2u + 1u) * 128u + (unsigned)(p * 2 + (role ^ 1))) * 64u;

        float xvA = 0.f, nzvA = 0.f, xvB = 0.f, nzvB = 0.f;
        if (tid < 128 && t < Tt - 1) {
            xvA = x[xbaseA]; nzvA = noise[nzbaseA];
            xvB = x[xbaseB]; nzvB = noise[nzbaseB];
        }
        float pselA, poutA, pselB, poutB;

        GATES_PUB(A)          // publish hA(t) early
        GATES_PUB(B)          // covers A-flight; publish hB(t)
        OWN(A)                // more A-flight cover
        POLL(A)
        TAIL(A)               // wA(t+1), wxA(t+1), outputsA(t)
        OWN(B)                // covers B-flight (plus all of A's tail)
        POLL(B)
        TAIL(B)
        BAR_LGKM();           // wxuB / partner-h writes visible for next iteration

        obaseA += (size_t)Bb * Oo;  obaseB += (size_t)Bb * Oo;
        nzbaseA += (size_t)Bb * Ff; nzbaseB += (size_t)Bb * Ff;
        swbaseA += (size_t)Bb * Ff; swbaseB += (size_t)Bb * Ff;
        xbaseA += Ff;               xbaseB += Ff;
    }

#undef GATES_PUB
#undef OWN
#undef POLL
#undef TAIL

    // ---- per-row selection-sum partials (role-0 blocks) ----
    if (role == 0) {
        redA[tid] = (tid < 128) ? ssumA : 0.f;
        redB[tid] = (tid < 128) ? ssumB : 0.f;
        __syncthreads();
        for (int s = 256; s > 0; s >>= 1) {
            if (tid < s) { redA[tid] += redA[tid + s]; redB[tid] += redB[tid + s]; }
            __syncthreads();
        }
        if (tid == 0) { partials[rA] = redA[0]; partials[rB] = redB[0]; }
    }
}

__global__ void finalize_kernel(const float* __restrict__ partials, float* __restrict__ out_scalar) {
    __shared__ float red[128];
    int t = threadIdx.x;
    red[t] = partials[t];
    __syncthreads();
    for (int s = 64; s > 0; s >>= 1) {
        if (t < s) red[t] += red[t + s];
        __syncthreads();
    }
    if (t == 0) out_scalar[0] = red[0];
}

extern "C" void kernel_launch(void* const* d_in, const int* in_sizes, int n_in,
                              void* d_out, int out_size, void* d_ws, size_t ws_size,
                              hipStream_t stream) {
    const float* x     = (const float*)d_in[0];
    const float* noise = (const float*)d_in[1];
    const float* w_ih  = (const float*)d_in[2];
    const float* w_hh  = (const float*)d_in[3];
    const float* b_ih  = (const float*)d_in[4];
    const float* b_hh  = (const float*)d_in[5];
    const float* W_out = (const float*)d_in[6];
    const float* b_out = (const float*)d_in[7];
    const float* W_sel = (const float*)d_in[8];
    const float* b_sel = (const float*)d_in[9];

    unsigned* wsu = (unsigned*)d_ws;
    float* out = (float*)d_out;
    float* outputs = out;                               // [T,B,O]
    float* nsel    = out + (size_t)Tt * Bb * Oo;        // scalar
    float* selw    = nsel + 1;                          // [T,B,F]
    float* partials = (float*)(wsu + P_PART);

    pack_kernel<<<(2 * NW * 512 + 255) / 256, 256, 0, stream>>>(w_ih, w_hh, W_sel, W_out, wsu);
    zero_hx<<<HX_U32 / 256, 256, 0, stream>>>(wsu + P_HX);
    gru_kernel<<<128, 512, 0, stream>>>(x, noise, b_ih, b_hh, b_out, b_sel,
                                        wsu, outputs, selw, partials);
    finalize_kernel<<<1, 128, 0, stream>>>(partials, nsel);
}